// Round 1
// baseline (889.888 us; speedup 1.0000x reference)
//
#include <hip/hip_runtime.h>
#include <hip/hip_fp16.h>

#define BB 32
#define IN_CAPS 1152
#define IN_DIM 64
#define NUM_CAPS 32
#define OUT_DIM 64
#define NCOL 2048            // NUM_CAPS*OUT_DIM
#define ICHUNK 32
#define NCHUNK 36            // 1152/32

// ---- workspace layout (bytes) ----
#define HAT_ELEMS  ((size_t)BB * IN_CAPS * NCOL)            // fp16
#define OFF_PART   (HAT_ELEMS * 2)
#define PART_ELEMS ((size_t)NCHUNK * BB * NCOL)             // fp32
#define OFF_LOGIT  (OFF_PART + PART_ELEMS * 4)
#define LOGIT_ELEMS ((size_t)BB * IN_CAPS * NUM_CAPS)       // fp32
#define OFF_OUT1   (OFF_LOGIT + LOGIT_ELEMS * 4)
#define OFF_OUT2   (OFF_OUT1 + (size_t)BB * NCOL * 4)

// ============================================================
// Kernel 1: hat[b,i,c,q] = sum_p x[b,i,p] * W[i,c,p,q], stored fp16.
// Grid (2, 1152): blockIdx.y = i, blockIdx.x = 1024-column half.
// Each thread: 4 consecutive q (one c), all 32 b in registers.
// Every W element is loaded exactly once across the grid.
// ============================================================
__global__ __launch_bounds__(256, 2)
void gemm_hat(const float* __restrict__ x, const float* __restrict__ W,
              __half* __restrict__ hat)
{
    const int i = blockIdx.y;
    const int colbase = blockIdx.x * 1024 + threadIdx.x * 4;
    const int c  = colbase >> 6;
    const int q0 = colbase & 63;

    __shared__ float xt[IN_DIM][BB];   // [p][b]
    {
        const int t  = threadIdx.x;
        const int b  = t >> 3;
        const int pg = (t & 7) * 8;
        const float* xp = x + ((size_t)b * IN_CAPS + i) * IN_DIM + pg;
        float4 v0 = *(const float4*)xp;
        float4 v1 = *(const float4*)(xp + 4);
        xt[pg + 0][b] = v0.x; xt[pg + 1][b] = v0.y;
        xt[pg + 2][b] = v0.z; xt[pg + 3][b] = v0.w;
        xt[pg + 4][b] = v1.x; xt[pg + 5][b] = v1.y;
        xt[pg + 6][b] = v1.z; xt[pg + 7][b] = v1.w;
    }
    __syncthreads();

    float4 acc[BB];
    #pragma unroll
    for (int b = 0; b < BB; ++b) acc[b] = make_float4(0.f, 0.f, 0.f, 0.f);

    const float* wp = W + ((size_t)i * NUM_CAPS + c) * IN_DIM * OUT_DIM + q0;
    #pragma unroll 4
    for (int p = 0; p < IN_DIM; ++p) {
        const float4 w4 = *(const float4*)wp; wp += OUT_DIM;
        #pragma unroll
        for (int bg = 0; bg < 8; ++bg) {
            const float4 xv = *(const float4*)(&xt[p][bg * 4]);
            acc[bg*4+0].x += xv.x * w4.x; acc[bg*4+0].y += xv.x * w4.y;
            acc[bg*4+0].z += xv.x * w4.z; acc[bg*4+0].w += xv.x * w4.w;
            acc[bg*4+1].x += xv.y * w4.x; acc[bg*4+1].y += xv.y * w4.y;
            acc[bg*4+1].z += xv.y * w4.z; acc[bg*4+1].w += xv.y * w4.w;
            acc[bg*4+2].x += xv.z * w4.x; acc[bg*4+2].y += xv.z * w4.y;
            acc[bg*4+2].z += xv.z * w4.z; acc[bg*4+2].w += xv.z * w4.w;
            acc[bg*4+3].x += xv.w * w4.x; acc[bg*4+3].y += xv.w * w4.y;
            acc[bg*4+3].z += xv.w * w4.z; acc[bg*4+3].w += xv.w * w4.w;
        }
    }

    #pragma unroll
    for (int b = 0; b < BB; ++b) {
        const float4 a = acc[b];
        __half2 h01 = __floats2half2_rn(a.x, a.y);
        __half2 h23 = __floats2half2_rn(a.z, a.w);
        uint2 pk;
        pk.x = *reinterpret_cast<unsigned int*>(&h01);
        pk.y = *reinterpret_cast<unsigned int*>(&h23);
        *reinterpret_cast<uint2*>(hat + ((size_t)b * IN_CAPS + i) * NCOL + colbase) = pk;
    }
}

// ============================================================
// Routing pass. Wave processes one (b,i): coalesced fp16 tile load,
// logits (dot over q), softmax over c, weighted partial sum over i.
// Lane mapping: element e = k*512 + lane*8 + j  ->  c = 8k + (lane>>3),
// q = (lane&7)*8 + j.  ROUND 1: logits = bias (broadcast). ROUND 2:
// logits = bias + dot(hat,out1), written out. ROUND 3: logits_in + dot.
// ============================================================
template<int ROUND>
__global__ __launch_bounds__(256, 2)
void route_pass(const __half* __restrict__ hat,
                const float* __restrict__ out_prev,
                const float* __restrict__ logits_in,
                float* __restrict__ logits_out,
                float* __restrict__ partials)
{
    const int chunk = blockIdx.x;
    const int b     = blockIdx.y;
    const int wave  = threadIdx.x >> 6;
    const int lane  = threadIdx.x & 63;
    const int g     = lane >> 3;         // c = 8k + g
    const int q0    = (lane & 7) * 8;

    float outv[4][8];
    if (ROUND >= 2) {
        #pragma unroll
        for (int k = 0; k < 4; ++k) {
            const int c = 8 * k + g;
            const float* op = out_prev + ((size_t)b * NUM_CAPS + c) * OUT_DIM + q0;
            float4 o0 = *(const float4*)op;
            float4 o1 = *(const float4*)(op + 4);
            outv[k][0] = o0.x; outv[k][1] = o0.y; outv[k][2] = o0.z; outv[k][3] = o0.w;
            outv[k][4] = o1.x; outv[k][5] = o1.y; outv[k][6] = o1.z; outv[k][7] = o1.w;
        }
    }

    float acc[4][8];
    #pragma unroll
    for (int k = 0; k < 4; ++k)
        #pragma unroll
        for (int j = 0; j < 8; ++j) acc[k][j] = 0.f;

    for (int t = 0; t < 8; ++t) {
        const int i = chunk * ICHUNK + wave * 8 + t;
        const __half* hp = hat + ((size_t)b * IN_CAPS + i) * NCOL;

        float hf[4][8];
        #pragma unroll
        for (int k = 0; k < 4; ++k) {
            float4 raw = *(const float4*)(hp + k * 512 + lane * 8);
            union { float4 f; __half2 h[4]; } u; u.f = raw;
            #pragma unroll
            for (int j2 = 0; j2 < 4; ++j2) {
                float2 fv = __half22float2(u.h[j2]);
                hf[k][2 * j2]     = fv.x;
                hf[k][2 * j2 + 1] = fv.y;
            }
        }

        float lg[4];
        if (ROUND == 1) {
            #pragma unroll
            for (int k = 0; k < 4; ++k)
                lg[k] = logits_in[i * NUM_CAPS + 8 * k + g];
        } else {
            float d[4];
            #pragma unroll
            for (int k = 0; k < 4; ++k) {
                float s = 0.f;
                #pragma unroll
                for (int j = 0; j < 8; ++j) s += hf[k][j] * outv[k][j];
                s += __shfl_xor(s, 1);
                s += __shfl_xor(s, 2);
                s += __shfl_xor(s, 4);
                d[k] = s;
            }
            #pragma unroll
            for (int k = 0; k < 4; ++k) {
                if (ROUND == 2)
                    lg[k] = logits_in[i * NUM_CAPS + 8 * k + g] + d[k];
                else
                    lg[k] = logits_in[((size_t)b * IN_CAPS + i) * NUM_CAPS + 8 * k + g] + d[k];
            }
            if (ROUND == 2 && (lane & 7) == 0) {
                #pragma unroll
                for (int k = 0; k < 4; ++k)
                    logits_out[((size_t)b * IN_CAPS + i) * NUM_CAPS + 8 * k + g] = lg[k];
            }
        }

        // softmax over 32 c's (4 in-lane, 8 lane groups via xor 8/16/32)
        float mx = fmaxf(fmaxf(lg[0], lg[1]), fmaxf(lg[2], lg[3]));
        mx = fmaxf(mx, __shfl_xor(mx, 8));
        mx = fmaxf(mx, __shfl_xor(mx, 16));
        mx = fmaxf(mx, __shfl_xor(mx, 32));
        float ex[4];
        float se = 0.f;
        #pragma unroll
        for (int k = 0; k < 4; ++k) { ex[k] = __expf(lg[k] - mx); se += ex[k]; }
        se += __shfl_xor(se, 8);
        se += __shfl_xor(se, 16);
        se += __shfl_xor(se, 32);
        const float inv = 1.0f / se;

        #pragma unroll
        for (int k = 0; k < 4; ++k) {
            const float cc = ex[k] * inv;
            #pragma unroll
            for (int j = 0; j < 8; ++j) acc[k][j] += cc * hf[k][j];
        }
    }

    // cross-wave reduce (deterministic, no atomics)
    __shared__ float red[4][NCOL];
    #pragma unroll
    for (int k = 0; k < 4; ++k)
        #pragma unroll
        for (int j = 0; j < 8; ++j)
            red[wave][(8 * k + g) * 64 + q0 + j] = acc[k][j];
    __syncthreads();

    for (int e = threadIdx.x; e < NCOL; e += 256) {
        float s = red[0][e] + red[1][e] + red[2][e] + red[3][e];
        partials[((size_t)chunk * BB + b) * NCOL + e] = s;
    }
}

// ============================================================
// Reduce partials over chunks + squash. One wave per (b,c), lane = q.
// ============================================================
__global__ __launch_bounds__(256)
void reduce_squash(const float* __restrict__ partials, float* __restrict__ out)
{
    const int gw   = blockIdx.x * 4 + (threadIdx.x >> 6);
    const int lane = threadIdx.x & 63;
    const int b = gw >> 5;
    const int c = gw & 31;

    float s = 0.f;
    #pragma unroll 4
    for (int k = 0; k < NCHUNK; ++k)
        s += partials[((size_t)k * BB + b) * NCOL + c * OUT_DIM + lane];

    float sq = s * s;
    #pragma unroll
    for (int m = 1; m < 64; m <<= 1) sq += __shfl_xor(sq, m);

    const float scale = sq / (1.f + sq) * rsqrtf(sq);
    out[((size_t)b * NUM_CAPS + c) * OUT_DIM + lane] = s * scale;
}

extern "C" void kernel_launch(void* const* d_in, const int* in_sizes, int n_in,
                              void* d_out, int out_size, void* d_ws, size_t ws_size,
                              hipStream_t stream)
{
    const float* x    = (const float*)d_in[0];
    const float* W    = (const float*)d_in[1];
    const float* bias = (const float*)d_in[2];
    float* out = (float*)d_out;

    char* ws = (char*)d_ws;
    __half* hat     = (__half*)ws;
    float* partials = (float*)(ws + OFF_PART);
    float* logits   = (float*)(ws + OFF_LOGIT);
    float* out1     = (float*)(ws + OFF_OUT1);
    float* out2     = (float*)(ws + OFF_OUT2);

    gemm_hat<<<dim3(2, IN_CAPS), 256, 0, stream>>>(x, W, hat);

    route_pass<1><<<dim3(NCHUNK, BB), 256, 0, stream>>>(hat, nullptr, bias, nullptr, partials);
    reduce_squash<<<256, 256, 0, stream>>>(partials, out1);

    route_pass<2><<<dim3(NCHUNK, BB), 256, 0, stream>>>(hat, out1, bias, logits, partials);
    reduce_squash<<<256, 256, 0, stream>>>(partials, out2);

    route_pass<3><<<dim3(NCHUNK, BB), 256, 0, stream>>>(hat, out2, logits, nullptr, partials);
    reduce_squash<<<256, 256, 0, stream>>>(partials, out);
}